// Round 2
// 657.627 us; speedup vs baseline: 1.1098x; 1.1098x over previous
//
#include <hip/hip_runtime.h>
#include <hip/hip_bf16.h>

typedef short s16x8 __attribute__((ext_vector_type(8)));
typedef short s16x4 __attribute__((ext_vector_type(4)));
typedef float f32x4 __attribute__((ext_vector_type(4)));
typedef unsigned int u32x4 __attribute__((ext_vector_type(4)));
typedef unsigned int u32x2 __attribute__((ext_vector_type(2)));

__device__ __forceinline__ float b2f(unsigned short u) {
  unsigned int v = ((unsigned int)u) << 16;
  return __builtin_bit_cast(float, v);
}
__device__ __forceinline__ unsigned short f2b(float f) {
  __hip_bfloat16 h = __float2bfloat16(f);
  return __builtin_bit_cast(unsigned short, h);
}
// async 16B global->LDS DMA; LDS dest = wave-uniform base + lane*16
__device__ __forceinline__ void async_ld16(const unsigned short* g, unsigned short* l) {
  __builtin_amdgcn_global_load_lds(
      (const __attribute__((address_space(1))) void*)g,
      (__attribute__((address_space(3))) void*)l, 16, 0, 0);
}

// ---------------- cast x (fp32 -> bf16), 4 elems/thread ----------------
__global__ __launch_bounds__(256) void cast_x_kernel(const float* __restrict__ x,
                                                     unsigned short* __restrict__ xb) {
  int i = (blockIdx.x * 256 + threadIdx.x) * 4;
  f32x4 v = *(const f32x4*)(x + i);
  u32x2 o;
  o[0] = (unsigned)f2b(v[0]) | ((unsigned)f2b(v[1]) << 16);
  o[1] = (unsigned)f2b(v[2]) | ((unsigned)f2b(v[3]) << 16);
  *(u32x2*)(xb + i) = o;
}

// ---------------- transpose + cast W [K][N] fp32 -> Wt [N][K] bf16 ----------------
__global__ __launch_bounds__(256) void wtrans_kernel(const float* __restrict__ W,
                                                     unsigned short* __restrict__ Wt,
                                                     int K, int N) {
  __shared__ float tile[64][65];
  int n0 = blockIdx.x * 64, k0 = blockIdx.y * 64;
  int tx = threadIdx.x & 63, ty = threadIdx.x >> 6;
  #pragma unroll
  for (int i = ty; i < 64; i += 4) tile[i][tx] = W[(long)(k0 + i) * N + n0 + tx];
  __syncthreads();
  #pragma unroll
  for (int i = ty; i < 64; i += 4) Wt[(long)(n0 + i) * K + k0 + tx] = f2b(tile[tx][i]);
}

// ---------------- bf16 MFMA GEMM: C[M][N] = A[M][K] @ Bt[N][K]^T + bias ----------------
// 256x256 tile, BK=64, 512 threads = 8 waves (2M x 4N), 8-phase pipelined schedule
// (T2 swizzle + T3/T4 counted-vmcnt + T5 setprio). LDS 128 KiB: per matrix 2 parity
// x 2 half slots of 128x64 bf16. Chunk swizzle: physical chunk cp of row r holds
// logical k-chunk cp ^ (r&7) -> ds_read_b128 frag reads are <=2-way bank aliased.
// vmcnt(6) only at phases 4 and 8 (3 half-tiles = 6 loads stay in flight).

#define BAR() __builtin_amdgcn_s_barrier()
#define PRIO1() __builtin_amdgcn_s_setprio(1)
#define PRIO0() __builtin_amdgcn_s_setprio(0)
#define VMW(n) asm volatile("s_waitcnt vmcnt(" #n ")" ::: "memory")

template<bool BF16OUT>
__global__ __launch_bounds__(512, 2) void gemm8p_kernel(
    const unsigned short* __restrict__ A, int lda,
    const unsigned short* __restrict__ Bt0, int ldb,
    const float* __restrict__ bias,
    void* __restrict__ Cv, int N, int K,
    int rows_per_batch, long bstride) {
  __shared__ unsigned short lds[65536];   // 128 KiB: A slots [0,32768), B slots [32768,65536)
  const int tid = threadIdx.x;
  const int lane = tid & 63, wid = tid >> 6;
  const int m0 = blockIdx.y * 256, n0 = blockIdx.x * 256;
  const int wm = (wid >> 2) * 128, wn = (wid & 3) * 64;
  const int fm = lane & 15, fq = lane >> 4;
  const int kc0 = (fq ^ (fm & 7)) * 8;   // swizzled chunk (elements) for ks=0
  const int kc1 = kc0 ^ 32;              // ks=1

  const unsigned short* Bt = Bt0;
  if (rows_per_batch) Bt += (long)(m0 / rows_per_batch) * bstride;

  // staging source pointers (bytes); j in {0,1}: chunk C=(wid*2+j)*64+lane of a 128x64 half
  const char* sA0; const char* sA1; const char* sB0; const char* sB1;
  {
    const int C0 = (wid * 2) * 64 + lane;
    const int r0 = C0 >> 3, cg0 = (C0 & 7) ^ (r0 & 7);
    const int C1 = (wid * 2 + 1) * 64 + lane;
    const int r1 = C1 >> 3, cg1 = (C1 & 7) ^ (r1 & 7);
    sA0 = (const char*)(A + (long)(m0 + r0) * lda + cg0 * 8);
    sA1 = (const char*)(A + (long)(m0 + r1) * lda + cg1 * 8);
    sB0 = (const char*)(Bt + (long)(n0 + r0) * ldb + cg0 * 8);
    sB1 = (const char*)(Bt + (long)(n0 + r1) * ldb + cg1 * 8);
  }
  const long hA = (long)lda * 256;   // byte stride of 128 rows
  const long hB = (long)ldb * 256;
  const int ldso = wid * 1024;       // wave-uniform LDS chunk-block offset (ushorts)

#define STG_A(P, h, kt) do { \
    async_ld16((const unsigned short*)(sA0 + (h) * hA + (long)(kt) * 128), \
               lds + ((P) * 2 + (h)) * 8192 + ldso); \
    async_ld16((const unsigned short*)(sA1 + (h) * hA + (long)(kt) * 128), \
               lds + ((P) * 2 + (h)) * 8192 + ldso + 512); \
  } while (0)
#define STG_B(P, h, kt) do { \
    async_ld16((const unsigned short*)(sB0 + (h) * hB + (long)(kt) * 128), \
               lds + 32768 + ((P) * 2 + (h)) * 8192 + ldso); \
    async_ld16((const unsigned short*)(sB1 + (h) * hB + (long)(kt) * 128), \
               lds + 32768 + ((P) * 2 + (h)) * 8192 + ldso + 512); \
  } while (0)

  // frag-read slot bases (ushorts) for this wave, per parity
  const int aBp0 = (wm >> 7) * 8192;
  const int aBp1 = 16384 + (wm >> 7) * 8192;
  const int bBp0 = 32768 + (wn >> 7) * 8192 + (wn & 64) * 64;
  const int bBp1 = 49152 + (wn >> 7) * 8192 + (wn & 64) * 64;

  s16x8 afr[4][2], bf0[2][2], bf1[2][2];
  f32x4 acc[8][4] = {};

#define LDA_(base, mq) do { _Pragma("unroll") \
    for (int mi = 0; mi < 4; mi++) { \
      const int ro = (base) + (((mq) * 64 + mi * 16 + fm) & 127) * 64; \
      afr[mi][0] = *(const s16x8*)(lds + ro + kc0); \
      afr[mi][1] = *(const s16x8*)(lds + ro + kc1); \
    } } while (0)
#define LDB_(base, nq, dst) do { _Pragma("unroll") \
    for (int ni = 0; ni < 2; ni++) { \
      const int ro = (base) + ((nq) * 32 + ni * 16 + fm) * 64; \
      dst[ni][0] = *(const s16x8*)(lds + ro + kc0); \
      dst[ni][1] = *(const s16x8*)(lds + ro + kc1); \
    } } while (0)
#define MMQ(mq, nq, bfr) do { _Pragma("unroll") \
    for (int ks = 0; ks < 2; ks++) { _Pragma("unroll") \
      for (int mi = 0; mi < 4; mi++) { _Pragma("unroll") \
        for (int ni = 0; ni < 2; ni++) \
          acc[(mq) * 4 + mi][(nq) * 2 + ni] = __builtin_amdgcn_mfma_f32_16x16x32_bf16( \
              afr[mi][ks], bfr[ni][ks], acc[(mq) * 4 + mi][(nq) * 2 + ni], 0, 0, 0); \
      } } } while (0)

  // prologue: tile0 -> parity0 (4 halves), tile1 -> parity1 (B halves + A half0)
  STG_A(0, 0, 0); STG_A(0, 1, 0); STG_B(0, 0, 0); STG_B(0, 1, 0);
  STG_B(1, 0, 1); STG_B(1, 1, 1); STG_A(1, 0, 1);
  VMW(6);   // tile0's 8 loads complete; tile1's 6 stay in flight
  BAR();

  const int NIT = K >> 7;   // iterations of 2 K-tiles (BK=64)
  #pragma unroll 1
  for (int i = 0; i < NIT; i++) {
    const int kt1 = 2 * i + 1, ktE = 2 * i + 2, ktO = 2 * i + 3;
    const bool st = (i + 1 < NIT);
    // ph1: tile even, quadrant (mq0,nq0); stage odd-tile A half1 (read at ph5)
    LDA_(aBp0, 0); LDB_(bBp0, 0, bf0);
    STG_A(1, 1, kt1);
    BAR(); PRIO1(); MMQ(0, 0, bf0); PRIO0(); BAR();
    // ph2: (mq0,nq1)
    LDB_(bBp0, 1, bf1);
    BAR(); PRIO1(); MMQ(0, 1, bf1); PRIO0(); BAR();
    // ph3: (mq1,nq1); even-B slots free after ph2 -> restage for tile ktE
    LDA_(aBp0, 1);
    if (st) { STG_B(0, 0, ktE); STG_B(0, 1, ktE); }
    BAR(); PRIO1(); MMQ(1, 1, bf1); PRIO0(); BAR();
    // ph4: (mq1,nq0); even-A half0 free after ph3
    if (st) STG_A(0, 0, ktE);
    BAR(); PRIO1(); MMQ(1, 0, bf0); PRIO0();
    if (st) { VMW(6); } else { VMW(0); }   // guarantees odd-tile halves (<=ph1) landed
    BAR();
    // ph5: tile odd, (mq0,nq0); even-A half1 free after ph3
    LDA_(aBp1, 0); LDB_(bBp1, 0, bf0);
    if (st) STG_A(0, 1, ktE);
    BAR(); PRIO1(); MMQ(0, 0, bf0); PRIO0(); BAR();
    // ph6: (mq0,nq1)
    LDB_(bBp1, 1, bf1);
    BAR(); PRIO1(); MMQ(0, 1, bf1); PRIO0(); BAR();
    // ph7: (mq1,nq1); odd-B slots free after ph6 -> stage tile ktO
    LDA_(aBp1, 1);
    if (st) { STG_B(1, 0, ktO); STG_B(1, 1, ktO); }
    BAR(); PRIO1(); MMQ(1, 1, bf1); PRIO0(); BAR();
    // ph8: (mq1,nq0); odd-A half0 free after ph7
    if (st) STG_A(1, 0, ktO);
    BAR(); PRIO1(); MMQ(1, 0, bf0); PRIO0();
    VMW(6);   // guarantees even-tile halves (<=ph5) landed before next ph1
    BAR();
  }

  // epilogue: D row = mg*16 + fq*4 + r, col = ng*16 + fm (per-wave 128x64)
  #pragma unroll
  for (int ng = 0; ng < 4; ng++) {
    const int col = n0 + wn + ng * 16 + fm;
    const float bv = bias[col];
    #pragma unroll
    for (int mg = 0; mg < 8; mg++) {
      #pragma unroll
      for (int r = 0; r < 4; r++) {
        const long row = m0 + wm + mg * 16 + fq * 4 + r;
        const float v = acc[mg][ng][r] + bv;
        if (BF16OUT) ((unsigned short*)Cv)[row * N + col] = f2b(v);
        else         ((float*)Cv)[row * N + col] = v;
      }
    }
  }
}

// ---------------- A-pass ----------------
// Unnormalized A_t[e][d] = sum_t (exp(q[t,e]) * kinv[t]) * exp(k[t,d]) and
// denom partials D[e] = sum_t exp(q[t,e]); per chunk of 1024 t. MFMA contraction.
// LDS held TRANSPOSED ([e][t], stride 36) so frag assembly is ds_read_b64 pairs.
__global__ __launch_bounds__(256) void apass_kernel(
    const unsigned short* __restrict__ qkv,
    float* __restrict__ Ap,   // [4][128][64e][64d]
    float* __restrict__ Dp) { // [4][8][1024]
  __shared__ unsigned short qT[64 * 36 + 8];  // [e][t]
  __shared__ unsigned short kT[64 * 36 + 8];  // [d][t]
  __shared__ float dled[64];
  const int tid = threadIdx.x;
  const int chunk = blockIdx.x, g = blockIdx.y;
  const int b = g >> 4, h = g & 15;
  const int w = tid >> 6, lane = tid & 63;
  const int fm = lane & 15, fq = lane >> 4;
  const int tl = tid >> 3;        // staging row t 0..31
  const int c0 = (tid & 7) * 8;   // staging col e/d

  if (tid < 64) dled[tid] = 0.f;

  const long row0 = (long)(b * 4096 + chunk * 1024 + tl);
  const unsigned short* qptr = qkv + row0 * 3072 + h * 64 + c0;
  const unsigned short* kptr = qptr + 1024;

  f32x4 acc[4] = {};   // wave w owns e-rows [w*16, w*16+16), tiles ni over d
  float dacc[8] = {};

  for (int ks = 0; ks < 32; ks++) {
    const long roff = (long)(ks * 32) * 3072;
    u32x4 qv = *(const u32x4*)(qptr + roff);
    u32x4 kv = *(const u32x4*)(kptr + roff);
    float qe[8], ke[8];
    #pragma unroll
    for (int i = 0; i < 4; i++) {
      qe[2*i]   = __expf(b2f((unsigned short)(qv[i] & 0xffffu)));
      qe[2*i+1] = __expf(b2f((unsigned short)(qv[i] >> 16)));
      ke[2*i]   = __expf(b2f((unsigned short)(kv[i] & 0xffffu)));
      ke[2*i+1] = __expf(b2f((unsigned short)(kv[i] >> 16)));
    }
    float p = 0.f;
    #pragma unroll
    for (int i = 0; i < 8; i++) p += ke[i];
    p += __shfl_xor(p, 1);
    p += __shfl_xor(p, 2);
    p += __shfl_xor(p, 4);          // 8 lanes sharing a t-row now hold row sum
    const float kinv = 1.0f / p;
    #pragma unroll
    for (int i = 0; i < 8; i++) dacc[i] += qe[i];
    __syncthreads();   // prev iter's frag reads complete
    #pragma unroll
    for (int i = 0; i < 8; i++) {
      qT[(c0 + i) * 36 + tl] = f2b(qe[i] * kinv);
      kT[(c0 + i) * 36 + tl] = f2b(ke[i]);
    }
    __syncthreads();
    const int aoff = (w * 16 + fm) * 36 + fq * 8;
    s16x4 alo = *(const s16x4*)&qT[aoff];
    s16x4 ahi = *(const s16x4*)&qT[aoff + 4];
    s16x8 af = {alo[0], alo[1], alo[2], alo[3], ahi[0], ahi[1], ahi[2], ahi[3]};
    #pragma unroll
    for (int ni = 0; ni < 4; ni++) {
      const int boff = (ni * 16 + fm) * 36 + fq * 8;
      s16x4 blo = *(const s16x4*)&kT[boff];
      s16x4 bhi = *(const s16x4*)&kT[boff + 4];
      s16x8 bfr = {blo[0], blo[1], blo[2], blo[3], bhi[0], bhi[1], bhi[2], bhi[3]};
      acc[ni] = __builtin_amdgcn_mfma_f32_16x16x32_bf16(af, bfr, acc[ni], 0, 0, 0);
    }
  }
  float* ap = Ap + (long)(chunk * 128 + g) * 4096;
  #pragma unroll
  for (int ni = 0; ni < 4; ni++)
    #pragma unroll
    for (int r = 0; r < 4; r++)
      ap[(w * 16 + fq * 4 + r) * 64 + ni * 16 + fm] = acc[ni][r];
  #pragma unroll
  for (int i = 0; i < 8; i++) atomicAdd(&dled[c0 + i], dacc[i]);
  __syncthreads();
  if (tid < 64) Dp[(chunk * 8 + b) * 1024 + h * 64 + tid] = dled[tid];
}

// ---------------- M build: Mt[b][n][h*64+d] = sum_e (SCALE*A/den)[e][d] * Wproj[h*64+e][n] ----
__global__ __launch_bounds__(256) void mmake_kernel(
    const float* __restrict__ Ap,
    const float* __restrict__ Dp,
    const float* __restrict__ Wproj,
    unsigned short* __restrict__ Mt) {
  __shared__ float At[4096];  // [e][d]
  __shared__ float Wp[4096];  // [e][n]
  const int tid = threadIdx.x;
  const int n0 = blockIdx.x * 64;
  const int g = blockIdx.y;
  const int b = g >> 4, h = g & 15;
  #pragma unroll
  for (int j = 0; j < 16; j++) {
    int lin = tid + 256 * j;
    int e = lin >> 6, n = lin & 63;
    float s = 0.f, den = 0.f;
    #pragma unroll
    for (int c = 0; c < 4; c++) {
      s   += Ap[(long)(c * 128 + g) * 4096 + lin];
      den += Dp[(c * 8 + b) * 1024 + h * 64 + e];
    }
    At[lin] = 0.125f * s / den;   // SCALE = 64^-0.5
    Wp[lin] = Wproj[(long)(h * 64 + e) * 1024 + n0 + n];
  }
  __syncthreads();
  const int d = tid & 63, ng = tid >> 6;
  float a_reg[64];
  #pragma unroll
  for (int e = 0; e < 64; e++) a_reg[e] = At[e * 64 + d];
  #pragma unroll
  for (int nn = 0; nn < 16; nn++) {
    const int n = ng * 16 + nn;
    float s = 0.f;
    #pragma unroll
    for (int e = 0; e < 64; e++)
      s = fmaf(a_reg[e], Wp[e * 64 + n], s);   // Wp read is wave-uniform broadcast
    Mt[((long)b << 20) + (long)(n0 + n) * 1024 + h * 64 + d] = f2b(s);
  }
}

// ---------------- launch ----------------
extern "C" void kernel_launch(void* const* d_in, const int* in_sizes, int n_in,
                              void* d_out, int out_size, void* d_ws, size_t ws_size,
                              hipStream_t stream) {
  const float* x     = (const float*)d_in[0];
  const float* Wqkv  = (const float*)d_in[1];
  const float* bqkv  = (const float*)d_in[2];
  const float* Wproj = (const float*)d_in[3];
  const float* bproj = (const float*)d_in[4];
  float* out = (float*)d_out;

  char* ws = (char*)d_ws;
  unsigned short* xb  = (unsigned short*)(ws + 0);           //  67,108,864 B
  unsigned short* wqt = (unsigned short*)(ws + 67108864);    //   6,291,456 B
  unsigned short* qkv = (unsigned short*)(ws + 73400320);    // 201,326,592 B
  float*          ap  = (float*)        (ws + 274726912);    //   8,388,608 B
  float*          dp  = (float*)        (ws + 283115520);    //     131,072 B
  unsigned short* mt  = (unsigned short*)(ws + 283246592);   //  16,777,216 B (end ~300MB)

  cast_x_kernel<<<dim3(32768), dim3(256), 0, stream>>>(x, xb);
  wtrans_kernel<<<dim3(48, 16), dim3(256), 0, stream>>>(Wqkv, wqt, 1024, 3072);
  gemm8p_kernel<true><<<dim3(12, 128), dim3(512), 0, stream>>>(
      xb, 1024, wqt, 1024, bqkv, (void*)qkv, 3072, 1024, 0, 0);
  apass_kernel<<<dim3(4, 128), dim3(256), 0, stream>>>(qkv, ap, dp);
  mmake_kernel<<<dim3(16, 128), dim3(256), 0, stream>>>(ap, dp, Wproj, mt);
  gemm8p_kernel<false><<<dim3(4, 128), dim3(512), 0, stream>>>(
      qkv + 2048, 3072, mt, 1024, bproj, (void*)out, 1024, 1024, 4096, 1048576);
}